// Round 12
// baseline (220.744 us; speedup 1.0000x reference)
//
#include <hip/hip_runtime.h>
#include <hip/hip_bf16.h>

// B=1024, F=512, N=8 — pipeline (5 kernel dispatches):
//  1) prep: X=concat(vx,ax) bf16 | W1,W2 cast | WC | M2 (reordered K)
//  2) H = relu(X @ W1^T + b1) bf16 [1024,4096]            (8.6 GF)
//  3) ATT = relu(H_n @ W2_n^T + b2_n) bf16, batch 8       (4.3 GF)
//  4) conv gemm (r8/r11-exact): va-tile LDS reuse + max-pool epilogue
//     -> PM[v][b][pi][o] bf16                              (38.7 GF)
//  5) out gemm with inline combine: K reordered to pj*1024+pi*512+o so
//     combine = two coalesced short8 PM loads + max + bias  (2.1 GF)

typedef __attribute__((ext_vector_type(8))) short short8;
typedef __attribute__((ext_vector_type(4))) float f32x4;

__device__ __forceinline__ void gload16(const void* g, void* l) {
    __builtin_amdgcn_global_load_lds(
        (const __attribute__((address_space(1))) void*)g,
        (__attribute__((address_space(3))) void*)l, 16, 0, 0);
}

// ---------------------------------------------------------------------------
// r3/r6-proven bf16 MFMA GEMM: C = A[M,K] * B[N,K]^T (+bias, relu), batch z.
// ---------------------------------------------------------------------------
template<int BM, int BN, bool RELU, bool BIAS, bool OUT_BF16>
__global__ __launch_bounds__(256) void gemm_mfma(
    const __hip_bfloat16* __restrict__ A, int lda, long sA,
    const __hip_bfloat16* __restrict__ B, int ldb, long sB,
    void* __restrict__ Cv, int ldc, long sC,
    const float* __restrict__ bias, long sBias,
    int K)
{
    constexpr int MI = BM / 32, NI = BN / 32;
    constexpr int GA = BM / 16, GB = BN / 16;
    constexpr int nA = (GA * 2) / 4, nB = (GB * 2) / 4;
    __shared__ __align__(16) char As[128 * BM];
    __shared__ __align__(16) char Bs[128 * BN];

    const int z = blockIdx.z;
    A += (long)z * sA;
    B += (long)z * sB;
    const int bm = blockIdx.y * BM;
    const int bn = blockIdx.x * BN;
    const int t = threadIdx.x, lane = t & 63, wid = t >> 6;
    const int q = lane >> 4, lr = lane & 15;
    const int wrow = (wid >> 1) * (BM / 2), wcol = (wid & 1) * (BN / 2);

    const int m_loc = lane >> 2;
    const int cst = ((lane & 3) - (m_loc >> 1)) & 3;
    const long abase = ((long)(bm + m_loc) * lda + cst * 8) * 2;
    const long bbase = ((long)(bn + m_loc) * ldb + cst * 8) * 2;
    const int ro = lr * 4;
    const int csel = (lr >> 1);

    f32x4 acc[MI][NI] = {};

    for (int k0 = 0; k0 < K; k0 += 64) {
        if (k0) __syncthreads();
        #pragma unroll
        for (int i = 0; i < nA; ++i) {
            int s = wid * nA + i, g = s % GA, h = s / GA;
            gload16((const char*)A + abase + ((long)g * 16 * lda + h * 32 + k0) * 2,
                    As + (h * (BM * 4) + g * 64) * 16);
        }
        #pragma unroll
        for (int i = 0; i < nB; ++i) {
            int s = wid * nB + i, g = s % GB, h = s / GB;
            gload16((const char*)B + bbase + ((long)g * 16 * ldb + h * 32 + k0) * 2,
                    Bs + (h * (BN * 4) + g * 64) * 16);
        }
        __syncthreads();

        #pragma unroll
        for (int ks = 0; ks < 2; ++ks) {
            short8 af[MI], bf[NI];
            #pragma unroll
            for (int mi = 0; mi < MI; ++mi) {
                int u = ks * (BM * 4) + ((wrow >> 4) + mi) * 64 + ro + ((q + csel) & 3);
                af[mi] = *(const short8*)(As + u * 16);
            }
            #pragma unroll
            for (int ni = 0; ni < NI; ++ni) {
                int u = ks * (BN * 4) + ((wcol >> 4) + ni) * 64 + ro + ((q + csel) & 3);
                bf[ni] = *(const short8*)(Bs + u * 16);
            }
            #pragma unroll
            for (int mi = 0; mi < MI; ++mi)
                #pragma unroll
                for (int ni = 0; ni < NI; ++ni)
                    acc[mi][ni] = __builtin_amdgcn_mfma_f32_16x16x32_bf16(
                        af[mi], bf[ni], acc[mi][ni], 0, 0, 0);
        }
    }

    #pragma unroll
    for (int mi = 0; mi < MI; ++mi) {
        #pragma unroll
        for (int ni = 0; ni < NI; ++ni) {
            int gn = bn + wcol + ni * 16 + lr;
            float bv = 0.f;
            if constexpr (BIAS) bv = bias[z * sBias + gn];
            #pragma unroll
            for (int r = 0; r < 4; ++r) {
                long gm = bm + wrow + mi * 16 + q * 4 + r;
                float v = acc[mi][ni][r] + bv;
                if constexpr (RELU) v = fmaxf(v, 0.f);
                if constexpr (OUT_BF16)
                    ((__hip_bfloat16*)Cv)[z * sC + gm * ldc + gn] = __float2bfloat16(v);
                else
                    ((float*)Cv)[z * sC + gm * ldc + gn] = v;
            }
        }
    }
}

// ---------------------------------------------------------------------------
// Conv GEMM — EXACT r8/r11 body (best measured: 46.1 µs). va tile staged to
// LDS once per 64-ch chunk (padded rows, stride 144 B), reused by 3 taps;
// B = WC via global_load_lds; epilogue max-pools -> PM bf16.
// Residual ~4.7e6 SQ_LDS_BANK_CONFLICT accepted (r9/r10 fixes cost more).
// ---------------------------------------------------------------------------
__global__ __launch_bounds__(256) void conv_gemm_pool(
    const float* __restrict__ vx,             // [1024,512] fp32
    const __hip_bfloat16* __restrict__ att,   // [1024,8,512] bf16
    const __hip_bfloat16* __restrict__ B,     // WC [1536,1536]
    __hip_bfloat16* __restrict__ PM)          // [3][1024][2][512] bf16
{
    constexpr int BM = 128, BN = 128, MI = 4, NI = 4;
    constexpr int GB = 8, nB = 4;
    const int ldb = 1536;
    __shared__ __align__(16) char VAs[160 * 144];
    __shared__ __align__(16) char Bs[128 * BN];

    const int bm = blockIdx.x * BM;
    const int bn = blockIdx.y * BN;
    const int t = threadIdx.x, lane = t & 63, wid = t >> 6;
    const int q = lane >> 4, lr = lane & 15;
    const int wrow = (wid >> 1) * 64, wcol = (wid & 1) * 64;

    const int m_loc = lane >> 2;
    const int cstB = ((lane & 3) - (m_loc >> 1)) & 3;
    const long bbase = ((long)(bn + m_loc) * ldb + cstB * 8) * 2;
    const int ro = lr * 4;
    const int csel = (lr >> 1);

    {
        int b = t >> 4, side = (t >> 3) & 1, w8 = t & 7;
        int pr = b * 10 + side * 9;
        short8 z8 = {0, 0, 0, 0, 0, 0, 0, 0};
        *(short8*)(VAs + (pr * 9 + w8) * 16) = z8;
    }

    int abase_[MI];
    #pragma unroll
    for (int mi = 0; mi < MI; ++mi) {
        int m = wrow + mi * 16 + lr;
        abase_[mi] = (((m >> 3) * 10 + (m & 7)) * 9 + q) * 16;
    }

    f32x4 acc[MI][NI] = {};

    for (int kk = 0; kk < 24; ++kk) {
        const int ki = kk - (kk / 3) * 3;
        const int c0 = (kk / 3) << 6;
        const int k0B = ki * 512 + c0;
        if (kk) __syncthreads();
        #pragma unroll
        for (int i = 0; i < nB; ++i) {
            int s = wid * nB + i, g = s % GB, h = s / GB;
            gload16((const char*)B + bbase + ((long)g * 16 * ldb + k0B + h * 32) * 2,
                    Bs + (h * (BN * 4) + g * 64) * 16);
        }
        if (ki == 0) {
            #pragma unroll
            for (int u = 0; u < 4; ++u) {
                int li = t + u * 256;
                int r = li >> 3, w8 = li & 7;
                int gm = bm + r;
                int c = c0 + w8 * 8;
                short8 a8 = *(const short8*)(att + (long)gm * 512 + c);
                const float* vp = vx + ((gm >> 3) << 9) + c;
                float4 v0 = *(const float4*)vp;
                float4 v1 = *(const float4*)(vp + 4);
                float vf[8] = {v0.x, v0.y, v0.z, v0.w, v1.x, v1.y, v1.z, v1.w};
                short8 val;
                #pragma unroll
                for (int j = 0; j < 8; ++j) {
                    union { short s; __hip_bfloat16 h; } ua; ua.s = a8[j];
                    union { __hip_bfloat16 h; short s; } ub;
                    ub.h = __float2bfloat16(__bfloat162float(ua.h) * vf[j]);
                    val[j] = ub.s;
                }
                int pr = (r >> 3) * 10 + 1 + (r & 7);
                *(short8*)(VAs + (pr * 9 + w8) * 16) = val;
            }
        }
        __syncthreads();

        #pragma unroll
        for (int ks = 0; ks < 2; ++ks) {
            short8 af[MI], bf[NI];
            #pragma unroll
            for (int mi = 0; mi < MI; ++mi)
                af[mi] = *(const short8*)(VAs + abase_[mi] + ki * 144 + ks * 64);
            #pragma unroll
            for (int ni = 0; ni < NI; ++ni) {
                int u = ks * (BN * 4) + ((wcol >> 4) + ni) * 64 + ro + ((q + csel) & 3);
                bf[ni] = *(const short8*)(Bs + u * 16);
            }
            #pragma unroll
            for (int mi = 0; mi < MI; ++mi)
                #pragma unroll
                for (int ni = 0; ni < NI; ++ni)
                    acc[mi][ni] = __builtin_amdgcn_mfma_f32_16x16x32_bf16(
                        af[mi], bf[ni], acc[mi][ni], 0, 0, 0);
        }
    }

    #pragma unroll
    for (int mi = 0; mi < MI; ++mi) {
        int rowbase = bm + wrow + mi * 16;
        int batch = (rowbase >> 3) + (q >> 1);
        int pi = q & 1;
        #pragma unroll
        for (int ni = 0; ni < NI; ++ni) {
            int gn = bn + wcol + ni * 16 + lr;
            int v = gn >> 9, o = gn & 511;
            float m = fmaxf(fmaxf(acc[mi][ni][0], acc[mi][ni][1]),
                            fmaxf(acc[mi][ni][2], acc[mi][ni][3]));
            PM[((long)v * 1024 + batch) * 1024 + pi * 512 + o] = __float2bfloat16(m);
        }
    }
}

// ---------------------------------------------------------------------------
// Out GEMM with inline combine, K reordered to k = pj*1024 + pi*512 + o.
// A[m=b][k] = max(PM[pj][b][pi][o], PM[pj+1][b][pi][o]) + c1b[o]
// Staging unit U: ks=U>>8, m=(U>>2)&63, slot=U&3, kc=(slot-(m>>1))&3,
// kb=k0+ks*32+kc*8 (8-aligned, single (pj,pi), o0=kb&511): two coalesced
// short8 PM loads + max + float4 bias -> ds_write_b128 (lane-linear).
// LDS layout = proven fragment-read shape (verified kc inverse: slot=(q+(lr>>1))&3
// -> chunk q). B = M2 [512, 2048 reordered] via proven global_load_lds.
// out = relu(A @ M2^T + c2b), fp32.
// ---------------------------------------------------------------------------
__global__ __launch_bounds__(256) void out_gemm(
    const __hip_bfloat16* __restrict__ PM,    // [3][1024][2][512] bf16
    const float* __restrict__ c1b,            // [512]
    const __hip_bfloat16* __restrict__ Bm,    // M2 [512,2048] (reordered K)
    const float* __restrict__ c2b,            // [512]
    float* __restrict__ out)                  // [1024,512] fp32
{
    constexpr int BM = 64, BN = 64, MI = 2, NI = 2;
    constexpr int GB = 4, nB = 2;
    const int ldb = 2048, K = 2048;
    __shared__ __align__(16) char As[512 * 16];
    __shared__ __align__(16) char Bs[512 * 16];

    const int bm = blockIdx.y * BM, bn = blockIdx.x * BN;
    const int t = threadIdx.x, lane = t & 63, wid = t >> 6;
    const int q = lane >> 4, lr = lane & 15;
    const int wrow = (wid >> 1) * 32, wcol = (wid & 1) * 32;
    const int m_loc = lane >> 2;
    const int cstB = ((lane & 3) - (m_loc >> 1)) & 3;
    const long bbase = ((long)(bn + m_loc) * ldb + cstB * 8) * 2;
    const int ro = lr * 4;
    const int csel = (lr >> 1);

    f32x4 acc[MI][NI] = {};

    for (int k0 = 0; k0 < K; k0 += 64) {
        if (k0) __syncthreads();
        // B staging (proven path)
        #pragma unroll
        for (int i = 0; i < nB; ++i) {
            int s = wid * nB + i, g = s % GB, h = s / GB;
            gload16((const char*)Bm + bbase + ((long)g * 16 * ldb + h * 32 + k0) * 2,
                    Bs + (h * (BN * 4) + g * 64) * 16);
        }
        // A staging: inline combine, coalesced short8 PM loads
        #pragma unroll
        for (int uu = 0; uu < 2; ++uu) {
            int U = t + uu * 256;
            int ks = U >> 8, m = (U >> 2) & 63, slot = U & 3;
            int kc = (slot - (m >> 1)) & 3;
            int kb = k0 + ks * 32 + kc * 8;   // 8-aligned
            int pj = kb >> 10, pi = (kb >> 9) & 1, o0 = kb & 511;
            int b = bm + m;
            const __hip_bfloat16* p0 =
                PM + (((long)pj * 1024 + b) * 2 + pi) * 512 + o0;
            short8 a0 = *(const short8*)p0;
            short8 a1 = *(const short8*)(p0 + 1024 * 1024);  // v = pj+1
            float4 f0 = *(const float4*)(c1b + o0);
            float4 f1 = *(const float4*)(c1b + o0 + 4);
            float bb[8] = {f0.x, f0.y, f0.z, f0.w, f1.x, f1.y, f1.z, f1.w};
            short8 val;
            #pragma unroll
            for (int j = 0; j < 8; ++j) {
                union { short s; __hip_bfloat16 h; } u0, u1;
                u0.s = a0[j]; u1.s = a1[j];
                float a = fmaxf(__bfloat162float(u0.h), __bfloat162float(u1.h));
                union { __hip_bfloat16 h; short s; } ub;
                ub.h = __float2bfloat16(a + bb[j]);
                val[j] = ub.s;
            }
            *(short8*)(As + U * 16) = val;
        }
        __syncthreads();

        #pragma unroll
        for (int ks = 0; ks < 2; ++ks) {
            short8 af[MI], bf[NI];
            #pragma unroll
            for (int mi = 0; mi < MI; ++mi) {
                int u = ks * 256 + ((wrow >> 4) + mi) * 64 + ro + ((q + csel) & 3);
                af[mi] = *(const short8*)(As + u * 16);
            }
            #pragma unroll
            for (int ni = 0; ni < NI; ++ni) {
                int u = ks * 256 + ((wcol >> 4) + ni) * 64 + ro + ((q + csel) & 3);
                bf[ni] = *(const short8*)(Bs + u * 16);
            }
            #pragma unroll
            for (int mi = 0; mi < MI; ++mi)
                #pragma unroll
                for (int ni = 0; ni < NI; ++ni)
                    acc[mi][ni] = __builtin_amdgcn_mfma_f32_16x16x32_bf16(
                        af[mi], bf[ni], acc[mi][ni], 0, 0, 0);
        }
    }

    #pragma unroll
    for (int mi = 0; mi < MI; ++mi) {
        #pragma unroll
        for (int ni = 0; ni < NI; ++ni) {
            int gn = bn + wcol + ni * 16 + lr;
            float bv = c2b[gn];
            #pragma unroll
            for (int r = 0; r < 4; ++r) {
                long gm = bm + wrow + mi * 16 + q * 4 + r;
                out[gm * 512 + gn] = fmaxf(acc[mi][ni][r] + bv, 0.f);
            }
        }
    }
}

// ---------------------------------------------------------------------------
// Merged prep: concat X | cast W1 | cast W2 | WC build | M2 build (K reorder)
// ---------------------------------------------------------------------------
__global__ __launch_bounds__(256) void prep_kernel(
    const float* __restrict__ vx, const float* __restrict__ ax,
    const float* __restrict__ W1, const float* __restrict__ W2,
    const float* __restrict__ c1w, const float* __restrict__ c2w,
    __hip_bfloat16* __restrict__ X,  __hip_bfloat16* __restrict__ W1b,
    __hip_bfloat16* __restrict__ W2b, __hip_bfloat16* __restrict__ WC,
    __hip_bfloat16* __restrict__ M2)
{
    int blk = blockIdx.x, t = threadIdx.x;
    if (blk < 2048) {                         // concat: 2048 blocks
        int i = blk * 256 + t, b = i >> 9, c = i & 511;
        X[((long)b << 10) + c]       = __float2bfloat16(vx[i]);
        X[((long)b << 10) + 512 + c] = __float2bfloat16(ax[i]);
    } else if (blk < 8192) {                  // cast W1 (4M) + W2 (2M), float4
        int j = (blk - 2048) * 256 + t;
        const float* src = (j < 1048576) ? W1 : W2;
        __hip_bfloat16* dst = (j < 1048576) ? W1b : W2b;
        int k = (j < 1048576) ? j : j - 1048576;
        float4 v = ((const float4*)src)[k];
        union { __hip_bfloat16 h[4]; short4 s; } u;
        u.h[0] = __float2bfloat16(v.x); u.h[1] = __float2bfloat16(v.y);
        u.h[2] = __float2bfloat16(v.z); u.h[3] = __float2bfloat16(v.w);
        ((short4*)dst)[k] = u.s;
    } else if (blk < 17408) {                 // WC: 9216 blocks
        int b2 = blk - 8192;
        int row = b2 / 6, col = (b2 % 6) * 256 + t;
        int v = row >> 9, o = row & 511;
        int ki = col >> 9, c = col & 511;
        const float* w = c1w + ((long)(o * 512 + c) * 3 + ki) * 3;
        float s = w[1];
        if (v != 0) s += w[0];
        if (v != 2) s += w[2];
        WC[(long)row * 1536 + col] = __float2bfloat16(s);
    } else {                                  // M2: 4096 blocks, reordered K
        int b2 = blk - 17408;
        int o2 = b2 >> 3, col = (b2 & 7) * 256 + t;   // col = pj*1024+pi*512+c
        int pj = col >> 10, pi = (col >> 9) & 1, c = col & 511;
        const float* w = c2w + (long)(o2 * 512 + c) * 9;
        float s = w[pi * 3 + pj] + w[pi * 3 + pj + 1]
                + w[(pi + 1) * 3 + pj] + w[(pi + 1) * 3 + pj + 1];
        M2[(long)o2 * 2048 + col] = __float2bfloat16(0.25f * s);
    }
}

extern "C" void kernel_launch(void* const* d_in, const int* in_sizes, int n_in,
                              void* d_out, int out_size, void* d_ws, size_t ws_size,
                              hipStream_t stream)
{
    const float* vx  = (const float*)d_in[0];
    const float* ax  = (const float*)d_in[1];
    const float* W1  = (const float*)d_in[2];
    const float* b1  = (const float*)d_in[3];
    const float* W2  = (const float*)d_in[4];
    const float* b2  = (const float*)d_in[5];
    const float* c1w = (const float*)d_in[6];
    const float* c1b = (const float*)d_in[7];
    const float* c2w = (const float*)d_in[8];
    const float* c2b = (const float*)d_in[9];
    float* out = (float*)d_out;
    char* w = (char*)d_ws;

    const long MiB = 1 << 20;
    __hip_bfloat16* Xbf   = (__hip_bfloat16*)(w + 0 * MiB);   // 2 MiB
    __hip_bfloat16* W1bf  = (__hip_bfloat16*)(w + 2 * MiB);   // 8 MiB
    __hip_bfloat16* Hbf   = (__hip_bfloat16*)(w + 10 * MiB);  // 8 MiB
    __hip_bfloat16* W2bf  = (__hip_bfloat16*)(w + 18 * MiB);  // 4 MiB
    __hip_bfloat16* ATTbf = (__hip_bfloat16*)(w + 22 * MiB);  // 8 MiB
    __hip_bfloat16* WCbf  = (__hip_bfloat16*)(w + 30 * MiB);  // 4.5 MiB
    __hip_bfloat16* PM    = (__hip_bfloat16*)(w + 35 * MiB);  // 6 MiB bf16
    __hip_bfloat16* M2bf  = (__hip_bfloat16*)(w + 41 * MiB);  // 2 MiB (end 43)

    // 1) merged prep
    prep_kernel<<<21504, 256, 0, stream>>>(vx, ax, W1, W2, c1w, c2w,
                                           Xbf, W1bf, W2bf, WCbf, M2bf);

    // 2) H = relu(X @ W1^T + b1): M=1024, N=4096, K=1024
    gemm_mfma<128, 128, true, true, true><<<dim3(32, 8, 1), 256, 0, stream>>>(
        Xbf, 1024, 0, W1bf, 1024, 0, Hbf, 4096, 0, b1, 0, 1024);

    // 3) ATT = relu(H_n @ W2_n^T + b2_n): M=1024, N=512, K=512, batch 8
    gemm_mfma<128, 128, true, true, true><<<dim3(4, 8, 8), 256, 0, stream>>>(
        Hbf, 4096, 512, W2bf, 512, 262144, ATTbf, 4096, 512, b2, 512, 512);

    // 4) conv gemm: r11-exact va-tile-reuse + fused max-pool (38.7 GF)
    conv_gemm_pool<<<dim3(64, 12), 256, 0, stream>>>(vx, ATTbf, WCbf, PM);

    // 5) out gemm with inline combine: M=1024, N=512, K=2048
    out_gemm<<<dim3(8, 16), 256, 0, stream>>>(PM, c1b, M2bf, c2b, out);
}

// Round 13
// 206.199 us; speedup vs baseline: 1.0705x; 1.0705x over previous
//
#include <hip/hip_runtime.h>
#include <hip/hip_bf16.h>

// B=1024, F=512, N=8 — pipeline (6 kernel dispatches), best measured config
// (r11, 206.6 µs):
//  1) prep | 2) H gemm | 3) ATT gemm | 4) conv gemm + pool -> PM bf16
//  5) combine -> P bf16 | 6) out gemm
// Post-r12 note: inline-combine staging in the out gemm regressed twice
// (r9: scattered loads; r12: coalesced but latency-serialized) — the
// separate combine + global_load_lds out-GEMM is the keeper.

typedef __attribute__((ext_vector_type(8))) short short8;
typedef __attribute__((ext_vector_type(4))) float f32x4;

__device__ __forceinline__ void gload16(const void* g, void* l) {
    __builtin_amdgcn_global_load_lds(
        (const __attribute__((address_space(1))) void*)g,
        (__attribute__((address_space(3))) void*)l, 16, 0, 0);
}

// ---------------------------------------------------------------------------
// r3/r6-proven bf16 MFMA GEMM: C = A[M,K] * B[N,K]^T (+bias, relu), batch z.
// 256 thr (4 waves), tile BM x BN, wave owns (BM/2)x(BN/2), BK=64.
// Staging: coalesced global_load_lds_dwordx4 (16 rows x 64B), add-rotate
// chunk swizzle; fragment ds_read_b128. MFMA maps (m89/m91):
// A/B elem[m|n=lane&15][k=(lane>>4)*8+j]; C/D col=lane&15, row=(lane>>4)*4+r.
// ---------------------------------------------------------------------------
template<int BM, int BN, bool RELU, bool BIAS, bool OUT_BF16>
__global__ __launch_bounds__(256) void gemm_mfma(
    const __hip_bfloat16* __restrict__ A, int lda, long sA,
    const __hip_bfloat16* __restrict__ B, int ldb, long sB,
    void* __restrict__ Cv, int ldc, long sC,
    const float* __restrict__ bias, long sBias,
    int K)
{
    constexpr int MI = BM / 32, NI = BN / 32;
    constexpr int GA = BM / 16, GB = BN / 16;
    constexpr int nA = (GA * 2) / 4, nB = (GB * 2) / 4;
    __shared__ __align__(16) char As[128 * BM];
    __shared__ __align__(16) char Bs[128 * BN];

    const int z = blockIdx.z;
    A += (long)z * sA;
    B += (long)z * sB;
    const int bm = blockIdx.y * BM;
    const int bn = blockIdx.x * BN;
    const int t = threadIdx.x, lane = t & 63, wid = t >> 6;
    const int q = lane >> 4, lr = lane & 15;
    const int wrow = (wid >> 1) * (BM / 2), wcol = (wid & 1) * (BN / 2);

    const int m_loc = lane >> 2;
    const int cst = ((lane & 3) - (m_loc >> 1)) & 3;
    const long abase = ((long)(bm + m_loc) * lda + cst * 8) * 2;
    const long bbase = ((long)(bn + m_loc) * ldb + cst * 8) * 2;
    const int ro = lr * 4;
    const int csel = (lr >> 1);

    f32x4 acc[MI][NI] = {};

    for (int k0 = 0; k0 < K; k0 += 64) {
        if (k0) __syncthreads();
        #pragma unroll
        for (int i = 0; i < nA; ++i) {
            int s = wid * nA + i, g = s % GA, h = s / GA;
            gload16((const char*)A + abase + ((long)g * 16 * lda + h * 32 + k0) * 2,
                    As + (h * (BM * 4) + g * 64) * 16);
        }
        #pragma unroll
        for (int i = 0; i < nB; ++i) {
            int s = wid * nB + i, g = s % GB, h = s / GB;
            gload16((const char*)B + bbase + ((long)g * 16 * ldb + h * 32 + k0) * 2,
                    Bs + (h * (BN * 4) + g * 64) * 16);
        }
        __syncthreads();

        #pragma unroll
        for (int ks = 0; ks < 2; ++ks) {
            short8 af[MI], bf[NI];
            #pragma unroll
            for (int mi = 0; mi < MI; ++mi) {
                int u = ks * (BM * 4) + ((wrow >> 4) + mi) * 64 + ro + ((q + csel) & 3);
                af[mi] = *(const short8*)(As + u * 16);
            }
            #pragma unroll
            for (int ni = 0; ni < NI; ++ni) {
                int u = ks * (BN * 4) + ((wcol >> 4) + ni) * 64 + ro + ((q + csel) & 3);
                bf[ni] = *(const short8*)(Bs + u * 16);
            }
            #pragma unroll
            for (int mi = 0; mi < MI; ++mi)
                #pragma unroll
                for (int ni = 0; ni < NI; ++ni)
                    acc[mi][ni] = __builtin_amdgcn_mfma_f32_16x16x32_bf16(
                        af[mi], bf[ni], acc[mi][ni], 0, 0, 0);
        }
    }

    #pragma unroll
    for (int mi = 0; mi < MI; ++mi) {
        #pragma unroll
        for (int ni = 0; ni < NI; ++ni) {
            int gn = bn + wcol + ni * 16 + lr;
            float bv = 0.f;
            if constexpr (BIAS) bv = bias[z * sBias + gn];
            #pragma unroll
            for (int r = 0; r < 4; ++r) {
                long gm = bm + wrow + mi * 16 + q * 4 + r;
                float v = acc[mi][ni][r] + bv;
                if constexpr (RELU) v = fmaxf(v, 0.f);
                if constexpr (OUT_BF16)
                    ((__hip_bfloat16*)Cv)[z * sC + gm * ldc + gn] = __float2bfloat16(v);
                else
                    ((float*)Cv)[z * sC + gm * ldc + gn] = v;
            }
        }
    }
}

// ---------------------------------------------------------------------------
// Conv GEMM — r8/r11 body (best measured: 46.1 µs, ~830 TF). va tile staged
// to LDS once per 64-ch chunk (padded rows, stride 144 B), reused by 3 conv
// taps via +ki*144; B = WC via proven global_load_lds; epilogue max-pools
// 4-row windows -> PM bf16 (max commutes with monotone rounding).
// Residual ~4.7e6 SQ_LDS_BANK_CONFLICT accepted — r9/r10 layout fixes both
// cost more in staging VALU than the conflicts (HW conflict behavior not
// captured by static bank model).
// ---------------------------------------------------------------------------
__global__ __launch_bounds__(256) void conv_gemm_pool(
    const float* __restrict__ vx,             // [1024,512] fp32
    const __hip_bfloat16* __restrict__ att,   // [1024,8,512] bf16
    const __hip_bfloat16* __restrict__ B,     // WC [1536,1536]
    __hip_bfloat16* __restrict__ PM)          // [3][1024][2][512] bf16
{
    constexpr int BM = 128, BN = 128, MI = 4, NI = 4;
    constexpr int GB = 8, nB = 4;
    const int ldb = 1536;
    __shared__ __align__(16) char VAs[160 * 144];   // 23040 B (padded rows)
    __shared__ __align__(16) char Bs[128 * BN];     // 16384 B

    const int bm = blockIdx.x * BM;           // 64 blocks
    const int bn = blockIdx.y * BN;           // 12 blocks
    const int t = threadIdx.x, lane = t & 63, wid = t >> 6;
    const int q = lane >> 4, lr = lane & 15;
    const int wrow = (wid >> 1) * 64, wcol = (wid & 1) * 64;

    const int m_loc = lane >> 2;
    const int cstB = ((lane & 3) - (m_loc >> 1)) & 3;
    const long bbase = ((long)(bn + m_loc) * ldb + cstB * 8) * 2;
    const int ro = lr * 4;
    const int csel = (lr >> 1);

    // zero the 32 pad rows (pr = b*10 and b*10+9), 8 units each
    {
        int b = t >> 4, side = (t >> 3) & 1, w8 = t & 7;
        int pr = b * 10 + side * 9;
        short8 z8 = {0, 0, 0, 0, 0, 0, 0, 0};
        *(short8*)(VAs + (pr * 9 + w8) * 16) = z8;
    }

    // A-fragment read base per mi (add ki*144 + ks*64 at use)
    int abase_[MI];
    #pragma unroll
    for (int mi = 0; mi < MI; ++mi) {
        int m = wrow + mi * 16 + lr;
        abase_[mi] = (((m >> 3) * 10 + (m & 7)) * 9 + q) * 16;
    }

    f32x4 acc[MI][NI] = {};

    for (int kk = 0; kk < 24; ++kk) {
        const int ki = kk - (kk / 3) * 3;     // tap 0..2 (inner)
        const int c0 = (kk / 3) << 6;         // channel chunk (outer)
        const int k0B = ki * 512 + c0;        // B global k base
        if (kk) __syncthreads();
        // B staging (proven global_load_lds path)
        #pragma unroll
        for (int i = 0; i < nB; ++i) {
            int s = wid * nB + i, g = s % GB, h = s / GB;
            gload16((const char*)B + bbase + ((long)g * 16 * ldb + k0B + h * 32) * 2,
                    Bs + (h * (BN * 4) + g * 64) * 16);
        }
        // va staging: once per c0 chunk (ki==0), 4 units/thread
        if (ki == 0) {
            #pragma unroll
            for (int u = 0; u < 4; ++u) {
                int li = t + u * 256;         // 0..1023
                int r = li >> 3, w8 = li & 7;
                int gm = bm + r;              // global va row (b*8+i)
                int c = c0 + w8 * 8;
                short8 a8 = *(const short8*)(att + (long)gm * 512 + c);
                const float* vp = vx + ((gm >> 3) << 9) + c;
                float4 v0 = *(const float4*)vp;
                float4 v1 = *(const float4*)(vp + 4);
                float vf[8] = {v0.x, v0.y, v0.z, v0.w, v1.x, v1.y, v1.z, v1.w};
                short8 val;
                #pragma unroll
                for (int j = 0; j < 8; ++j) {
                    union { short s; __hip_bfloat16 h; } ua; ua.s = a8[j];
                    union { __hip_bfloat16 h; short s; } ub;
                    ub.h = __float2bfloat16(__bfloat162float(ua.h) * vf[j]);
                    val[j] = ub.s;
                }
                int pr = (r >> 3) * 10 + 1 + (r & 7);
                *(short8*)(VAs + (pr * 9 + w8) * 16) = val;
            }
        }
        __syncthreads();

        #pragma unroll
        for (int ks = 0; ks < 2; ++ks) {
            short8 af[MI], bf[NI];
            #pragma unroll
            for (int mi = 0; mi < MI; ++mi)
                af[mi] = *(const short8*)(VAs + abase_[mi] + ki * 144 + ks * 64);
            #pragma unroll
            for (int ni = 0; ni < NI; ++ni) {
                int u = ks * (BN * 4) + ((wcol >> 4) + ni) * 64 + ro + ((q + csel) & 3);
                bf[ni] = *(const short8*)(Bs + u * 16);
            }
            #pragma unroll
            for (int mi = 0; mi < MI; ++mi)
                #pragma unroll
                for (int ni = 0; ni < NI; ++ni)
                    acc[mi][ni] = __builtin_amdgcn_mfma_f32_16x16x32_bf16(
                        af[mi], bf[ni], acc[mi][ni], 0, 0, 0);
        }
    }

    #pragma unroll
    for (int mi = 0; mi < MI; ++mi) {
        int rowbase = bm + wrow + mi * 16;            // multiple of 16
        int batch = (rowbase >> 3) + (q >> 1);
        int pi = q & 1;
        #pragma unroll
        for (int ni = 0; ni < NI; ++ni) {
            int gn = bn + wcol + ni * 16 + lr;
            int v = gn >> 9, o = gn & 511;
            float m = fmaxf(fmaxf(acc[mi][ni][0], acc[mi][ni][1]),
                            fmaxf(acc[mi][ni][2], acc[mi][ni][3]));
            PM[((long)v * 1024 + batch) * 1024 + pi * 512 + o] = __float2bfloat16(m);
        }
    }
}

// ---------------------------------------------------------------------------
// Merged prep: concat X | cast W1 | cast W2 | WC build | M2 build
// ---------------------------------------------------------------------------
__global__ __launch_bounds__(256) void prep_kernel(
    const float* __restrict__ vx, const float* __restrict__ ax,
    const float* __restrict__ W1, const float* __restrict__ W2,
    const float* __restrict__ c1w, const float* __restrict__ c2w,
    __hip_bfloat16* __restrict__ X,  __hip_bfloat16* __restrict__ W1b,
    __hip_bfloat16* __restrict__ W2b, __hip_bfloat16* __restrict__ WC,
    __hip_bfloat16* __restrict__ M2)
{
    int blk = blockIdx.x, t = threadIdx.x;
    if (blk < 2048) {                         // concat: 2048 blocks
        int i = blk * 256 + t, b = i >> 9, c = i & 511;
        X[((long)b << 10) + c]       = __float2bfloat16(vx[i]);
        X[((long)b << 10) + 512 + c] = __float2bfloat16(ax[i]);
    } else if (blk < 8192) {                  // cast W1 (4M) + W2 (2M), float4
        int j = (blk - 2048) * 256 + t;
        const float* src = (j < 1048576) ? W1 : W2;
        __hip_bfloat16* dst = (j < 1048576) ? W1b : W2b;
        int k = (j < 1048576) ? j : j - 1048576;
        float4 v = ((const float4*)src)[k];
        union { __hip_bfloat16 h[4]; short4 s; } u;
        u.h[0] = __float2bfloat16(v.x); u.h[1] = __float2bfloat16(v.y);
        u.h[2] = __float2bfloat16(v.z); u.h[3] = __float2bfloat16(v.w);
        ((short4*)dst)[k] = u.s;
    } else if (blk < 17408) {                 // WC: 9216 blocks
        int b2 = blk - 8192;
        int row = b2 / 6, col = (b2 % 6) * 256 + t;
        int v = row >> 9, o = row & 511;
        int ki = col >> 9, c = col & 511;
        const float* w = c1w + ((long)(o * 512 + c) * 3 + ki) * 3;
        float s = w[1];
        if (v != 0) s += w[0];
        if (v != 2) s += w[2];
        WC[(long)row * 1536 + col] = __float2bfloat16(s);
    } else {                                  // M2: 4096 blocks
        int b2 = blk - 17408;
        int o2 = b2 >> 3, col = (b2 & 7) * 256 + t;
        int c = col >> 2, pi = (col >> 1) & 1, pj = col & 1;
        const float* w = c2w + (long)(o2 * 512 + c) * 9;
        float s = w[pi * 3 + pj] + w[pi * 3 + pj + 1]
                + w[(pi + 1) * 3 + pj] + w[(pi + 1) * 3 + pj + 1];
        M2[(long)o2 * 2048 + col] = __float2bfloat16(0.25f * s);
    }
}

// cross-variant max + conv1 bias -> P[b][o*4 + pi*2 + pj] bf16 (PM bf16 in)
__global__ __launch_bounds__(256) void combine_kernel(
    const __hip_bfloat16* __restrict__ PM, const float* __restrict__ c1b,
    __hip_bfloat16* __restrict__ P)
{
    int idx = blockIdx.x * 256 + threadIdx.x;   // b*512+o
    int b = idx >> 9, o = idx & 511;
    float bias = c1b[o];
    const long vs = 1024L * 1024;
    long base = (long)b * 1024 + o;
    float l0 = __bfloat162float(PM[base]);
    float l1 = __bfloat162float(PM[base + 512]);
    float m0 = __bfloat162float(PM[vs + base]);
    float m1 = __bfloat162float(PM[vs + base + 512]);
    float r0 = __bfloat162float(PM[2 * vs + base]);
    float r1 = __bfloat162float(PM[2 * vs + base + 512]);
    union { __hip_bfloat16 h[4]; short4 s; } u;
    u.h[0] = __float2bfloat16(fmaxf(l0, m0) + bias);
    u.h[1] = __float2bfloat16(fmaxf(m0, r0) + bias);
    u.h[2] = __float2bfloat16(fmaxf(l1, m1) + bias);
    u.h[3] = __float2bfloat16(fmaxf(m1, r1) + bias);
    ((short4*)(P + (long)b * 2048 + o * 4))[0] = u.s;
}

extern "C" void kernel_launch(void* const* d_in, const int* in_sizes, int n_in,
                              void* d_out, int out_size, void* d_ws, size_t ws_size,
                              hipStream_t stream)
{
    const float* vx  = (const float*)d_in[0];
    const float* ax  = (const float*)d_in[1];
    const float* W1  = (const float*)d_in[2];
    const float* b1  = (const float*)d_in[3];
    const float* W2  = (const float*)d_in[4];
    const float* b2  = (const float*)d_in[5];
    const float* c1w = (const float*)d_in[6];
    const float* c1b = (const float*)d_in[7];
    const float* c2w = (const float*)d_in[8];
    const float* c2b = (const float*)d_in[9];
    float* out = (float*)d_out;
    char* w = (char*)d_ws;

    const long MiB = 1 << 20;
    __hip_bfloat16* Xbf   = (__hip_bfloat16*)(w + 0 * MiB);   // 2 MiB
    __hip_bfloat16* W1bf  = (__hip_bfloat16*)(w + 2 * MiB);   // 8 MiB
    __hip_bfloat16* Hbf   = (__hip_bfloat16*)(w + 10 * MiB);  // 8 MiB
    __hip_bfloat16* W2bf  = (__hip_bfloat16*)(w + 18 * MiB);  // 4 MiB
    __hip_bfloat16* ATTbf = (__hip_bfloat16*)(w + 22 * MiB);  // 8 MiB
    __hip_bfloat16* WCbf  = (__hip_bfloat16*)(w + 30 * MiB);  // 4.5 MiB
    __hip_bfloat16* PM    = (__hip_bfloat16*)(w + 35 * MiB);  // 6 MiB bf16
    __hip_bfloat16* Pbf   = (__hip_bfloat16*)(w + 41 * MiB);  // 4 MiB
    __hip_bfloat16* M2bf  = (__hip_bfloat16*)(w + 45 * MiB);  // 2 MiB (end 47)

    // 1) merged prep
    prep_kernel<<<21504, 256, 0, stream>>>(vx, ax, W1, W2, c1w, c2w,
                                           Xbf, W1bf, W2bf, WCbf, M2bf);

    // 2) H = relu(X @ W1^T + b1): M=1024, N=4096, K=1024
    gemm_mfma<128, 128, true, true, true><<<dim3(32, 8, 1), 256, 0, stream>>>(
        Xbf, 1024, 0, W1bf, 1024, 0, Hbf, 4096, 0, b1, 0, 1024);

    // 3) ATT = relu(H_n @ W2_n^T + b2_n): M=1024, N=512, K=512, batch 8
    gemm_mfma<128, 128, true, true, true><<<dim3(4, 8, 8), 256, 0, stream>>>(
        Hbf, 4096, 512, W2bf, 512, 262144, ATTbf, 4096, 512, b2, 512, 512);

    // 4) conv gemm: r8-exact va-tile-reuse + fused max-pool (38.7 GF)
    conv_gemm_pool<<<dim3(64, 12), 256, 0, stream>>>(vx, ATTbf, WCbf, PM);

    // 5) combine variants + bias -> P
    combine_kernel<<<2048, 256, 0, stream>>>(PM, c1b, Pbf);

    // 6) out = relu(P @ M2^T + c2b): M=1024, N=512, K=2048
    gemm_mfma<64, 64, true, true, false><<<dim3(8, 16, 1), 256, 0, stream>>>(
        Pbf, 2048, 0, M2bf, 2048, 0, out, 512, 0, c2b, 0, 2048);
}